// Round 6
// baseline (637.767 us; speedup 1.0000x reference)
//
#include <hip/hip_runtime.h>
#include <math.h>

typedef __attribute__((ext_vector_type(8))) short bf16x8;
typedef __attribute__((ext_vector_type(4))) float f32x4;
typedef __attribute__((ext_vector_type(8))) unsigned short u16x8;

#define DEVFN __device__ __forceinline__
#define AS1 __attribute__((address_space(1)))
#define AS3 __attribute__((address_space(3)))

DEVFN unsigned short f2bf(float f) {
    unsigned int u = __float_as_uint(f);
    u += 0x7fffu + ((u >> 16) & 1u);   // RNE; inputs are finite
    return (unsigned short)(u >> 16);
}

// ---------------- dual cast f32 -> bf16 (h and h'), 8 elems/thread ----------------
__global__ void cast2_kernel(const float* __restrict__ a, const float* __restrict__ b,
                             unsigned short* __restrict__ oa, unsigned short* __restrict__ ob,
                             int n8) {
    const float* in = blockIdx.y ? b : a;
    unsigned short* out = blockIdx.y ? ob : oa;
    int i = blockIdx.x * blockDim.x + threadIdx.x;
    if (i >= n8) return;
    const float4* p = reinterpret_cast<const float4*>(in) + (size_t)i * 2;
    float4 x = p[0], y = p[1];
    u16x8 o;
    o[0] = f2bf(x.x); o[1] = f2bf(x.y); o[2] = f2bf(x.z); o[3] = f2bf(x.w);
    o[4] = f2bf(y.x); o[5] = f2bf(y.y); o[6] = f2bf(y.z); o[7] = f2bf(y.w);
    reinterpret_cast<u16x8*>(out)[i] = o;
}

// ---------------- sum 4 fp32 partials -> bf16 ----------------
__global__ void sum4_cast_kernel(const float* __restrict__ p, size_t stride,
                                 unsigned short* __restrict__ out, int n8) {
    int i = blockIdx.x * blockDim.x + threadIdx.x;
    if (i >= n8) return;
    const float4* a = reinterpret_cast<const float4*>(p) + (size_t)i * 2;
    const float4* b = reinterpret_cast<const float4*>(p + stride) + (size_t)i * 2;
    const float4* c = reinterpret_cast<const float4*>(p + 2 * stride) + (size_t)i * 2;
    const float4* d = reinterpret_cast<const float4*>(p + 3 * stride) + (size_t)i * 2;
    u16x8 o;
#pragma unroll
    for (int j = 0; j < 2; ++j) {
        float4 va = a[j], vb = b[j], vc = c[j], vd = d[j];
        o[4 * j + 0] = f2bf(va.x + vb.x + vc.x + vd.x);
        o[4 * j + 1] = f2bf(va.y + vb.y + vc.y + vd.y);
        o[4 * j + 2] = f2bf(va.z + vb.z + vc.z + vd.z);
        o[4 * j + 3] = f2bf(va.w + vb.w + vc.w + vd.w);
    }
    reinterpret_cast<u16x8*>(out)[i] = o;
}

// ---------------- concat 3 bias vectors (512 each) ----------------
__global__ void concat_bias_kernel(const float* __restrict__ a,
                                   const float* __restrict__ b,
                                   const float* __restrict__ c,
                                   float* __restrict__ o) {
    int i = blockIdx.x * blockDim.x + threadIdx.x;
    if (i >= 1536) return;
    o[i] = i < 512 ? a[i] : (i < 1024 ? b[i - 512] : c[i - 1024]);
}

// ---------------- fused multi-matrix transpose f32 -> bf16 ----------------
struct TD { const float* in; unsigned short* out; int ldin, ldout, nbx, nby; };
struct TD6 { TD d[6]; };

__global__ void multi_transpose_kernel(TD6 t6) {
    TD d = t6.d[blockIdx.z];
    if ((int)blockIdx.x >= d.nbx || (int)blockIdx.y >= d.nby) return;
    __shared__ unsigned short tile[32][34];
    int c0 = blockIdx.x * 32, r0 = blockIdx.y * 32;
    int tx = threadIdx.x, ty = threadIdx.y;  // (32,8)
#pragma unroll
    for (int i = 0; i < 32; i += 8)
        tile[ty + i][tx] = f2bf(d.in[(size_t)(r0 + ty + i) * d.ldin + c0 + tx]);
    __syncthreads();
#pragma unroll
    for (int i = 0; i < 32; i += 8)
        d.out[(size_t)(c0 + ty + i) * d.ldout + r0 + tx] = tile[tx][ty + i];
}

// ---------------- bf16 matrix transpose (for V) ----------------
__global__ void transpose_bf16_kernel(const unsigned short* __restrict__ in, int ldin,
                                      unsigned short* __restrict__ out, int ldout) {
    __shared__ unsigned short tile[32][34];
    int c0 = blockIdx.x * 32, r0 = blockIdx.y * 32;
    int tx = threadIdx.x, ty = threadIdx.y;
#pragma unroll
    for (int i = 0; i < 32; i += 8)
        tile[ty + i][tx] = in[(size_t)(r0 + ty + i) * ldin + c0 + tx];
    __syncthreads();
#pragma unroll
    for (int i = 0; i < 32; i += 8)
        out[(size_t)(c0 + ty + i) * ldout + r0 + tx] = tile[tx][ty + i];
}

// ================= 256x256 minimal 2-phase GEMM (T3 recipe) =================
// C = A @ B^T. A:(M,K) bf16 lda, B:(N,K) bf16 ldb, K%64==0, M,N%256==0.
// 512 thr = 8 waves (2M x 4N); wave output 128x64 interleaved at 16-granularity:
// rows mi*32+wm*16 (mi 0..7), cols ni*64+wn*16 (ni 0..3).
// Per K-tile: STAGE(next) -> 24 asm ds_read_b128 (full tile) -> lgkmcnt(0) ->
// 64 MFMA -> vmcnt(0) -> s_barrier.  ONE barrier + ONE drain per K-tile; the
// staged loads get the whole ds+MFMA phase (~1300cy) to fly before the drain.
enum { P8_DMUL = 0, P8_F32 = 1 };

#define DSR(dst, base, IMM) \
    asm volatile("ds_read_b128 %0, %1 offset:%c2" : "=v"(dst) : "v"(base), "i"(IMM))

#define DSA2(mi)                                  \
    DSR(areg[mi][0], abase0, (mi) * 4096);        \
    DSR(areg[mi][1], abase1, (mi) * 4096);

#define DSB2(ni)                                  \
    DSR(breg[ni][0], bbase0, (ni) * 8192);        \
    DSR(breg[ni][1], bbase1, (ni) * 8192);

#define STAGEA(BUF, HALF, KT)                                                   \
    {                                                                           \
        const unsigned short* g0 = Ablk + (size_t)((HALF) * 128 + srow) * lda + (KT) * 64 + src8;       \
        const unsigned short* g1 = Ablk + (size_t)((HALF) * 128 + 64 + srow) * lda + (KT) * 64 + src8;  \
        unsigned short* d0 = &As[BUF][(HALF) * 8192 + (w * 64) * 8];            \
        unsigned short* d1 = &As[BUF][(HALF) * 8192 + (512 + w * 64) * 8];      \
        __builtin_amdgcn_global_load_lds((const AS1 void*)g0, (AS3 void*)d0, 16, 0, 0); \
        __builtin_amdgcn_global_load_lds((const AS1 void*)g1, (AS3 void*)d1, 16, 0, 0); \
    }

#define STAGEB(BUF, HALF, KT)                                                   \
    {                                                                           \
        const unsigned short* g0 = Bblk + (size_t)((HALF) * 128 + srow) * ldb + (KT) * 64 + src8;       \
        const unsigned short* g1 = Bblk + (size_t)((HALF) * 128 + 64 + srow) * ldb + (KT) * 64 + src8;  \
        unsigned short* d0 = &Bs[BUF][(HALF) * 8192 + (w * 64) * 8];            \
        unsigned short* d1 = &Bs[BUF][(HALF) * 8192 + (512 + w * 64) * 8];      \
        __builtin_amdgcn_global_load_lds((const AS1 void*)g0, (AS3 void*)d0, 16, 0, 0); \
        __builtin_amdgcn_global_load_lds((const AS1 void*)g1, (AS3 void*)d1, 16, 0, 0); \
    }

#define STAGE_ALL(BUF, KT) \
    STAGEA(BUF, 0, KT); STAGEB(BUF, 0, KT); STAGEB(BUF, 1, KT); STAGEA(BUF, 1, KT)

#define DS_ALL                                                      \
    DSA2(0) DSA2(1) DSA2(2) DSA2(3) DSA2(4) DSA2(5) DSA2(6) DSA2(7) \
    DSB2(0) DSB2(1) DSB2(2) DSB2(3)

#define MMAC_ALL                                                                \
    {                                                                           \
        __builtin_amdgcn_s_setprio(1);                                          \
        _Pragma("unroll") for (int mi = 0; mi < 8; ++mi)                        \
        _Pragma("unroll") for (int ni = 0; ni < 4; ++ni)                        \
        _Pragma("unroll") for (int kk = 0; kk < 2; ++kk)                        \
            acc[mi][ni] = __builtin_amdgcn_mfma_f32_16x16x32_bf16(              \
                areg[mi][kk], breg[ni][kk], acc[mi][ni], 0, 0, 0);              \
        __builtin_amdgcn_s_setprio(0);                                          \
    }

#define VMCNT0 asm volatile("s_waitcnt vmcnt(0)" ::: "memory")
#define BAR __builtin_amdgcn_s_barrier()
#define WAITDS                                          \
    asm volatile("s_waitcnt lgkmcnt(0)" ::: "memory");  \
    __builtin_amdgcn_sched_barrier(0)

template <int MODE>
__global__ __launch_bounds__(512, 2) void gemm2p_kernel(
    const unsigned short* __restrict__ A, int lda,
    const unsigned short* __restrict__ B, int ldb,
    void* __restrict__ Cv, int ldc, int K,
    const float* __restrict__ Dmul, int ldd, size_t zstride) {
    __shared__ alignas(16) unsigned short As[2][256 * 64];
    __shared__ alignas(16) unsigned short Bs[2][256 * 64];

    unsigned bx, by, zi = 0;
    if (MODE == P8_F32) {
        // z-grouped XCD mapping: z-chunk -> XCD pair; V z-slab (2MB) stays L2-hot
        unsigned gx = gridDim.x;
        unsigned L = (blockIdx.z * gridDim.y + blockIdx.y) * gx + blockIdx.x;
        unsigned xcd = L & 7u, slot = L >> 3;
        zi = xcd >> 1;
        unsigned t = slot * 2 + (xcd & 1u);
        bx = t & (gx - 1);
        by = t / gx;
    } else {
        unsigned nwg = gridDim.x * gridDim.y;
        unsigned bid = blockIdx.y * gridDim.x + blockIdx.x;
        unsigned cpx = nwg >> 3;
        bid = (bid & 7u) * cpx + (bid >> 3);
        bx = bid % gridDim.x;
        by = bid / gridDim.x;
    }
    size_t m0 = (size_t)by * 256, n0 = (size_t)bx * 256;

    int tid = threadIdx.x;
    int lane = tid & 63, w = tid >> 6;
    int wm = w >> 2, wn = w & 3;
    int lrow = lane & 15;

    const unsigned short* Ablk = A + m0 * lda + (size_t)zi * K;
    const unsigned short* Bblk = B + n0 * ldb + (size_t)zi * K;
    int src8 = ((lane & 7) ^ (lane >> 3)) * 8;  // pre-swizzled source col (elems)
    int srow = w * 8 + (lane >> 3);             // staging row within 64-row slab

    // LDS byte addresses for asm ds_read: row stride 128B, chunk 16B,
    // chunk index = ((kk<<2) + (lane>>4)) ^ (lane&7)  [matches staging swizzle;
    // read rows are == lane&7 (mod 8) since all row strides are multiples of 16]
    unsigned asBase = (unsigned)(uintptr_t)(AS3 const void*)&As[0][0];
    unsigned bsBase = (unsigned)(uintptr_t)(AS3 const void*)&Bs[0][0];
    unsigned cA0 = (unsigned)((((lane >> 4)) ^ (lane & 7)) * 16);
    unsigned cA1 = (unsigned)(((4 + (lane >> 4)) ^ (lane & 7)) * 16);
    unsigned aOff0 = asBase + (unsigned)((wm * 16 + lrow) * 128);
    unsigned bOff0 = bsBase + (unsigned)((wn * 16 + lrow) * 128);

    f32x4 acc[8][4];
#pragma unroll
    for (int i = 0; i < 8; ++i)
#pragma unroll
        for (int j = 0; j < 4; ++j)
#pragma unroll
            for (int r = 0; r < 4; ++r) acc[i][j][r] = 0.f;

    const int NT = K >> 6;
    bf16x8 areg[8][2], breg[4][2];
    float dreg[8][4][4];  // D prefetch (P8_DMUL only; else DCE'd)

    // prologue: stage tile 0, drain, barrier
    STAGE_ALL(0, 0);
    VMCNT0;
    BAR;

    // main loop (peeled last tile): ONE barrier + ONE vmcnt drain per K-tile
    for (int t = 0; t < NT - 1; ++t) {
        int buf = t & 1;
        unsigned boff = (unsigned)buf * 32768u;
        unsigned abase0 = aOff0 + boff + cA0;
        unsigned abase1 = aOff0 + boff + cA1;
        unsigned bbase0 = bOff0 + boff + cA0;
        unsigned bbase1 = bOff0 + boff + cA1;

        STAGE_ALL(buf ^ 1, t + 1);  // issue next-tile loads first; they fly
        DS_ALL;                     // 24 ds_read_b128 of current tile
        WAITDS;
        MMAC_ALL;                   // 64 MFMA
        VMCNT0;                     // next tile landed (had ~1300cy to fly)
        BAR;
    }

    // last tile: no stage; D-prefetch overlaps ds_read+MFMA
    {
        int buf = (NT - 1) & 1;
        unsigned boff = (unsigned)buf * 32768u;
        unsigned abase0 = aOff0 + boff + cA0;
        unsigned abase1 = aOff0 + boff + cA1;
        unsigned bbase0 = bOff0 + boff + cA0;
        unsigned bbase1 = bOff0 + boff + cA1;

        if (MODE == P8_DMUL) {
#pragma unroll
            for (int mi = 0; mi < 8; ++mi)
#pragma unroll
                for (int ni = 0; ni < 4; ++ni)
#pragma unroll
                    for (int r = 0; r < 4; ++r)
                        dreg[mi][ni][r] =
                            Dmul[(m0 + mi * 32 + wm * 16 + ((lane >> 4) << 2) + r) * (size_t)ldd +
                                 (n0 + ni * 64 + wn * 16 + (lane & 15))];
        }
        DS_ALL;
        WAITDS;
        MMAC_ALL;
    }

    // epilogue: C/D frag layout col=lane&15, row=(lane>>4)*4+r  [m89-verified]
#pragma unroll
    for (int mi = 0; mi < 8; ++mi) {
#pragma unroll
        for (int ni = 0; ni < 4; ++ni) {
            size_t gcol = n0 + ni * 64 + wn * 16 + (lane & 15);
#pragma unroll
            for (int r = 0; r < 4; ++r) {
                size_t grow = m0 + mi * 32 + wm * 16 + ((lane >> 4) << 2) + r;
                if (MODE == P8_DMUL) {
                    float v = acc[mi][ni][r] * dreg[mi][ni][r];
                    ((unsigned short*)Cv)[grow * (size_t)ldc + gcol] = f2bf(v);
                } else {
                    float* Cf = (float*)Cv + zi * zstride;
                    Cf[grow * (size_t)ldc + gcol] = acc[mi][ni][r];
                }
            }
        }
    }
}

// ---------------- 128x128 GEMM (2 blocks/CU) for small-N stages ----------------
enum { EP_BF16_BIAS = 0, EP_PRELU_GN = 4, EP_DUAL = 5 };

template <int MODE>
__global__ __launch_bounds__(256, 2) void gemm_bt_kernel(
    const unsigned short* __restrict__ A, int lda,
    const unsigned short* __restrict__ B, int ldb,
    void* __restrict__ Cv, int ldc, int K,
    const float* __restrict__ bias,
    const float* __restrict__ PA, const float* __restrict__ GW,
    const float* __restrict__ GB,
    const unsigned short* __restrict__ A2,
    const unsigned short* __restrict__ B2,
    const float* __restrict__ bias2) {
    __shared__ alignas(16) unsigned short As[2][128 * 64];
    __shared__ alignas(16) unsigned short Bs[2][128 * 64];

    unsigned nwg = gridDim.x * gridDim.y;
    unsigned bid = blockIdx.y * gridDim.x + blockIdx.x;
    unsigned cpx = nwg >> 3;
    bid = (bid & 7u) * cpx + (bid >> 3);
    unsigned bx = bid % gridDim.x, by = bid / gridDim.x;
    size_t m0 = (size_t)by * 128;
    size_t nB = (size_t)bx * 128;
    size_t ncol0 = nB;

    const unsigned short* Ause = A;
    const unsigned short* Buse = B;
    const float* bias_use = bias;
    bool apply_gelu = false;
    if (MODE == EP_DUAL) {
        unsigned half = gridDim.x >> 1;
        if (bx >= half) {  // C-branch: h' @ Cw + Cb -> cols 1024..2047
            nB = (size_t)(bx - half) * 128;
            ncol0 = 1024 + nB;
            Ause = A2; Buse = B2; bias_use = bias2;
        } else {
            apply_gelu = true;
        }
    }

    int tid = threadIdx.x;
    int lane = tid & 63, w = tid >> 6;
    int wr = w >> 1, wc = w & 1;
    int cif = lane & 15;
    int rif = (lane >> 4) << 2;

    f32x4 acc[4][4];
#pragma unroll
    for (int i = 0; i < 4; ++i)
#pragma unroll
        for (int j = 0; j < 4; ++j)
#pragma unroll
            for (int r = 0; r < 4; ++r) acc[i][j][r] = 0.f;

    const unsigned short* Ablk = Ause + m0 * lda;
    const unsigned short* Bblk = Buse + nB * ldb;
    int srccol = ((lane & 7) ^ (lane >> 3)) * 8;
    int srow = w * 32 + (lane >> 3);
    int nkt = K >> 6;

    auto stage = [&](int buf, int kt) {
        int k0 = kt << 6;
        unsigned short* la = &As[buf][w * 2048];
        unsigned short* lb = &Bs[buf][w * 2048];
#pragma unroll
        for (int i = 0; i < 4; ++i) {
            __builtin_amdgcn_global_load_lds(
                (const AS1 void*)(Ablk + (size_t)(srow + i * 8) * lda + k0 + srccol),
                (AS3 void*)(la + i * 512), 16, 0, 0);
            __builtin_amdgcn_global_load_lds(
                (const AS1 void*)(Bblk + (size_t)(srow + i * 8) * ldb + k0 + srccol),
                (AS3 void*)(lb + i * 512), 16, 0, 0);
        }
    };

    stage(0, 0);
    __syncthreads();

    for (int kt = 0; kt < nkt; ++kt) {
        int cur = kt & 1;
        if (kt + 1 < nkt) stage(cur ^ 1, kt + 1);

        const bf16x8* Ap = reinterpret_cast<const bf16x8*>(As[cur]);
        const bf16x8* Bp = reinterpret_cast<const bf16x8*>(Bs[cur]);
#pragma unroll
        for (int kk = 0; kk < 2; ++kk) {
            bf16x8 af[4], bfr[4];
#pragma unroll
            for (int mi = 0; mi < 4; ++mi) {
                int row = wr * 64 + mi * 16 + (lane & 15);
                int slot = ((kk << 2) + (lane >> 4)) ^ (row & 7);
                af[mi] = Ap[row * 8 + slot];
            }
#pragma unroll
            for (int ni = 0; ni < 4; ++ni) {
                int row = wc * 64 + ni * 16 + (lane & 15);
                int slot = ((kk << 2) + (lane >> 4)) ^ (row & 7);
                bfr[ni] = Bp[row * 8 + slot];
            }
#pragma unroll
            for (int mi = 0; mi < 4; ++mi)
#pragma unroll
                for (int ni = 0; ni < 4; ++ni)
                    acc[mi][ni] = __builtin_amdgcn_mfma_f32_16x16x32_bf16(
                        af[mi], bfr[ni], acc[mi][ni], 0, 0, 0);
        }
        __syncthreads();
    }

    if (MODE == EP_PRELU_GN) {
        float* Cf = (float*)Cv;
        float pbv[4], pav[4], gwv[4], gbv[4];
        size_t gcolv[4];
#pragma unroll
        for (int ni = 0; ni < 4; ++ni) {
            gcolv[ni] = ncol0 + wc * 64 + ni * 16 + cif;
            pbv[ni] = bias[gcolv[ni]];
            pav[ni] = PA[gcolv[ni]];
            gwv[ni] = GW[gcolv[ni]];
            gbv[ni] = GB[gcolv[ni]];
        }
#pragma unroll
        for (int mi = 0; mi < 4; ++mi) {
#pragma unroll
            for (int ni = 0; ni < 4; ++ni)
#pragma unroll
                for (int r = 0; r < 4; ++r) {
                    float v = acc[mi][ni][r] + pbv[ni];
                    acc[mi][ni][r] = v >= 0.f ? v : pav[ni] * v;
                }
#pragma unroll
            for (int p = 0; p < 2; ++p) {
                float s[4], ss[4];
#pragma unroll
                for (int r = 0; r < 4; ++r) {
                    float a0 = acc[mi][2 * p][r], a1 = acc[mi][2 * p + 1][r];
                    s[r] = a0 + a1;
                    ss[r] = a0 * a0 + a1 * a1;
                }
#pragma unroll
                for (int msk = 1; msk < 16; msk <<= 1)
#pragma unroll
                    for (int r = 0; r < 4; ++r) {
                        s[r] += __shfl_xor(s[r], msk);
                        ss[r] += __shfl_xor(ss[r], msk);
                    }
#pragma unroll
                for (int r = 0; r < 4; ++r) {
                    float mu = s[r] * (1.f / 32.f);
                    float inv = rsqrtf(ss[r] * (1.f / 32.f) - mu * mu + 1e-5f);
                    size_t grow = m0 + wr * 64 + mi * 16 + rif + r;
#pragma unroll
                    for (int q = 0; q < 2; ++q) {
                        int ni = 2 * p + q;
                        Cf[grow * (size_t)ldc + gcolv[ni]] =
                            (acc[mi][ni][r] - mu) * inv * gwv[ni] + gbv[ni];
                    }
                }
            }
        }
        return;
    }

#pragma unroll
    for (int mi = 0; mi < 4; ++mi) {
#pragma unroll
        for (int ni = 0; ni < 4; ++ni) {
            size_t gcol = ncol0 + wc * 64 + ni * 16 + cif;
            size_t bcol = nB + wc * 64 + ni * 16 + cif;
            float bval = bias_use ? bias_use[bcol] : 0.f;
#pragma unroll
            for (int r = 0; r < 4; ++r) {
                size_t grow = m0 + wr * 64 + mi * 16 + rif + r;
                float val = acc[mi][ni][r] + bval;
                if (MODE == EP_DUAL && apply_gelu)
                    val = 0.5f * val * (1.f + erff(val * 0.70710678118654752f));
                ((unsigned short*)Cv)[grow * (size_t)ldc + gcol] = f2bf(val);
            }
        }
    }
}

extern "C" void kernel_launch(void* const* d_in, const int* in_sizes, int n_in,
                              void* d_out, int out_size, void* d_ws, size_t ws_size,
                              hipStream_t stream) {
    constexpr int Nn = 8192, IND = 512, INTER = 512, HID = 1024, OUTD = 512;
    const float* h   = (const float*)d_in[0];
    const float* Dm  = (const float*)d_in[1];
    const float* hp  = (const float*)d_in[2];
    const float* Qw  = (const float*)d_in[3];
    const float* Qb  = (const float*)d_in[4];
    const float* Kw  = (const float*)d_in[5];
    const float* Kb  = (const float*)d_in[6];
    const float* Vw  = (const float*)d_in[7];
    const float* Vb  = (const float*)d_in[8];
    const float* Rw  = (const float*)d_in[9];
    const float* Rb  = (const float*)d_in[10];
    const float* Cw  = (const float*)d_in[11];
    const float* Cb  = (const float*)d_in[12];
    const float* Pw  = (const float*)d_in[13];
    const float* Pb  = (const float*)d_in[14];
    const float* pa  = (const float*)d_in[15];
    const float* gwt = (const float*)d_in[16];
    const float* gbt = (const float*)d_in[17];
    (void)in_sizes; (void)n_in; (void)out_size; (void)ws_size;

    char* ws = (char*)d_ws;
    size_t cur = 0;
    auto alloc = [&](size_t bytes) -> void* {
        void* p = ws + cur;
        cur += (bytes + 255) & ~(size_t)255;
        return p;
    };
    unsigned short* h_bf   = (unsigned short*)alloc((size_t)Nn * IND * 2);
    unsigned short* hp_bf  = (unsigned short*)alloc((size_t)Nn * OUTD * 2);
    unsigned short* QKVwT  = (unsigned short*)alloc((size_t)3 * INTER * IND * 2);
    float*          qkvb   = (float*)alloc((size_t)3 * INTER * 4);
    unsigned short* RwT    = (unsigned short*)alloc((size_t)INTER * HID * 2);
    unsigned short* CwT    = (unsigned short*)alloc((size_t)OUTD * HID * 2);
    unsigned short* PwT    = (unsigned short*)alloc((size_t)2 * HID * OUTD * 2);
    unsigned short* QKVm   = (unsigned short*)alloc((size_t)Nn * 3 * INTER * 2);
    unsigned short* VTm    = (unsigned short*)alloc((size_t)Nn * INTER * 2);
    unsigned short* Sm     = (unsigned short*)alloc((size_t)Nn * Nn * 2);      // 134 MB scores
    float*          hret32 = (float*)alloc((size_t)4 * Nn * INTER * 4);        // K-split partials
    unsigned short* hretbf = (unsigned short*)alloc((size_t)Nn * INTER * 2);
    unsigned short* comb   = Sm;  // overlay: combined (8192x2048 bf16) over dead scores

    unsigned short* Qm = QKVm;
    unsigned short* Km = QKVm + INTER;
    unsigned short* Vm = QKVm + 2 * INTER;
    const int ldqkv = 3 * INTER;

    dim3 tb(32, 8);
    int n8 = Nn * IND / 8;
    cast2_kernel<<<dim3(n8 / 256, 2), 256, 0, stream>>>(h, hp, h_bf, hp_bf, n8);

    TD6 t6;
    t6.d[0] = {Qw, QKVwT,                          INTER, IND,     16, 16};
    t6.d[1] = {Kw, QKVwT + (size_t)INTER * IND,    INTER, IND,     16, 16};
    t6.d[2] = {Vw, QKVwT + (size_t)2 * INTER * IND,INTER, IND,     16, 16};
    t6.d[3] = {Rw, RwT,                            HID,   INTER,   32, 16};
    t6.d[4] = {Cw, CwT,                            HID,   OUTD,    32, 16};
    t6.d[5] = {Pw, PwT,                            OUTD,  2 * HID, 16, 64};
    multi_transpose_kernel<<<dim3(32, 64, 6), tb, 0, stream>>>(t6);
    concat_bias_kernel<<<6, 256, 0, stream>>>(Qb, Kb, Vb, qkvb);

    // fused QKV projection: (8192 x 1536) = h @ [Qw|Kw|Vw] + [Qb|Kb|Vb]
    gemm_bt_kernel<EP_BF16_BIAS><<<dim3(3 * INTER / 128, Nn / 128), 256, 0, stream>>>(
        h_bf, IND, QKVwT, IND, QKVm, ldqkv, IND, qkvb,
        nullptr, nullptr, nullptr, nullptr, nullptr, nullptr);
    transpose_bf16_kernel<<<dim3(INTER / 32, Nn / 32), tb, 0, stream>>>(Vm, ldqkv, VTm, Nn);

    // stage2: scores = D .* (Q K^T), full 8192x8192 bf16  [2-phase 256^2]
    gemm2p_kernel<P8_DMUL><<<dim3(Nn / 256, Nn / 256), 512, 0, stream>>>(
        Qm, ldqkv, Km, ldqkv, Sm, Nn, INTER, Dm, Nn, 0);

    // stage3: hret = scores @ V, K-split x4 into fp32 partials  [2-phase 256^2]
    gemm2p_kernel<P8_F32><<<dim3(OUTD / 256, Nn / 256, 4), 512, 0, stream>>>(
        Sm, Nn, VTm, Nn, hret32, INTER, Nn / 4, nullptr, 0, (size_t)Nn * INTER);
    sum4_cast_kernel<<<(Nn * INTER / 8) / 256, 256, 0, stream>>>(
        hret32, (size_t)Nn * INTER, hretbf, Nn * INTER / 8);

    // combined[:, :1024] = gelu(hret @ Rw + Rb) ; combined[:, 1024:] = h' @ Cw + Cb
    gemm_bt_kernel<EP_DUAL><<<dim3(2 * HID / 128, Nn / 128), 256, 0, stream>>>(
        hretbf, INTER, RwT, INTER, comb, 2 * HID, INTER, Rb,
        nullptr, nullptr, nullptr, hp_bf, CwT, Cb);

    // x = combined @ Pw + Pb -> PReLU -> GroupNorm -> d_out (fp32)
    gemm_bt_kernel<EP_PRELU_GN><<<dim3(OUTD / 128, Nn / 128), 256, 0, stream>>>(
        comb, 2 * HID, PwT, 2 * HID, d_out, OUTD, 2 * HID, Pb,
        pa, gwt, gbt, nullptr, nullptr, nullptr);
}

// Round 7
// 368.493 us; speedup vs baseline: 1.7307x; 1.7307x over previous
//
#include <hip/hip_runtime.h>
#include <math.h>

typedef __attribute__((ext_vector_type(8))) short bf16x8;
typedef __attribute__((ext_vector_type(4))) float f32x4;
typedef __attribute__((ext_vector_type(8))) unsigned short u16x8;

#define DEVFN __device__ __forceinline__
#define AS1 __attribute__((address_space(1)))
#define AS3 __attribute__((address_space(3)))

DEVFN unsigned short f2bf(float f) {
    unsigned int u = __float_as_uint(f);
    u += 0x7fffu + ((u >> 16) & 1u);   // RNE; inputs are finite
    return (unsigned short)(u >> 16);
}
DEVFN float bf2f(unsigned short u) {
    unsigned int x = ((unsigned int)u) << 16;
    return __uint_as_float(x);
}

// ---------------- dual cast f32 -> bf16 (h and h'), 8 elems/thread ----------------
__global__ void cast2_kernel(const float* __restrict__ a, const float* __restrict__ b,
                             unsigned short* __restrict__ oa, unsigned short* __restrict__ ob,
                             int n8) {
    const float* in = blockIdx.y ? b : a;
    unsigned short* out = blockIdx.y ? ob : oa;
    int i = blockIdx.x * blockDim.x + threadIdx.x;
    if (i >= n8) return;
    const float4* p = reinterpret_cast<const float4*>(in) + (size_t)i * 2;
    float4 x = p[0], y = p[1];
    u16x8 o;
    o[0] = f2bf(x.x); o[1] = f2bf(x.y); o[2] = f2bf(x.z); o[3] = f2bf(x.w);
    o[4] = f2bf(y.x); o[5] = f2bf(y.y); o[6] = f2bf(y.z); o[7] = f2bf(y.w);
    reinterpret_cast<u16x8*>(out)[i] = o;
}

// ---------------- sum 4 bf16 partials -> bf16 ----------------
__global__ void sum4b_kernel(const unsigned short* __restrict__ p, size_t stride,
                             unsigned short* __restrict__ out, int n8) {
    int i = blockIdx.x * blockDim.x + threadIdx.x;
    if (i >= n8) return;
    u16x8 a = reinterpret_cast<const u16x8*>(p)[i];
    u16x8 b = reinterpret_cast<const u16x8*>(p + stride)[i];
    u16x8 c = reinterpret_cast<const u16x8*>(p + 2 * stride)[i];
    u16x8 d = reinterpret_cast<const u16x8*>(p + 3 * stride)[i];
    u16x8 o;
#pragma unroll
    for (int j = 0; j < 8; ++j)
        o[j] = f2bf(bf2f(a[j]) + bf2f(b[j]) + bf2f(c[j]) + bf2f(d[j]));
    reinterpret_cast<u16x8*>(out)[i] = o;
}

// ---------------- concat 3 bias vectors (512 each) ----------------
__global__ void concat_bias_kernel(const float* __restrict__ a,
                                   const float* __restrict__ b,
                                   const float* __restrict__ c,
                                   float* __restrict__ o) {
    int i = blockIdx.x * blockDim.x + threadIdx.x;
    if (i >= 1536) return;
    o[i] = i < 512 ? a[i] : (i < 1024 ? b[i - 512] : c[i - 1024]);
}

// ---------------- fused multi-matrix transpose f32 -> bf16 ----------------
struct TD { const float* in; unsigned short* out; int ldin, ldout, nbx, nby; };
struct TD6 { TD d[6]; };

__global__ void multi_transpose_kernel(TD6 t6) {
    TD d = t6.d[blockIdx.z];
    if ((int)blockIdx.x >= d.nbx || (int)blockIdx.y >= d.nby) return;
    __shared__ unsigned short tile[32][34];
    int c0 = blockIdx.x * 32, r0 = blockIdx.y * 32;
    int tx = threadIdx.x, ty = threadIdx.y;  // (32,8)
#pragma unroll
    for (int i = 0; i < 32; i += 8)
        tile[ty + i][tx] = f2bf(d.in[(size_t)(r0 + ty + i) * d.ldin + c0 + tx]);
    __syncthreads();
#pragma unroll
    for (int i = 0; i < 32; i += 8)
        d.out[(size_t)(c0 + ty + i) * d.ldout + r0 + tx] = tile[tx][ty + i];
}

// ---------------- bf16 matrix transpose (for V) ----------------
__global__ void transpose_bf16_kernel(const unsigned short* __restrict__ in, int ldin,
                                      unsigned short* __restrict__ out, int ldout) {
    __shared__ unsigned short tile[32][34];
    int c0 = blockIdx.x * 32, r0 = blockIdx.y * 32;
    int tx = threadIdx.x, ty = threadIdx.y;
#pragma unroll
    for (int i = 0; i < 32; i += 8)
        tile[ty + i][tx] = in[(size_t)(r0 + ty + i) * ldin + c0 + tx];
    __syncthreads();
#pragma unroll
    for (int i = 0; i < 32; i += 8)
        out[(size_t)(c0 + ty + i) * ldout + r0 + tx] = tile[tx][ty + i];
}

// ---------------- 128x128 GEMM (2 blocks/CU), all stages ----------------
// C = epi(A @ B^T). 4 waves (2x2), 4x4 16x16x32 frags/wave, double-buffered
// LDS, one __syncthreads per K-tile. 2-resident blocks: one block's epilogue
// traffic overlaps the other's MFMA loop (m114 wave-level overlap).
// EP_DMUL_LDS: stage full 128x128 fp32 D-tile into dead LDS (coalesced
// float4, 2x512B rows per wave-instr), then per-lane ds_read + mul (fixes
// the 64-scalar-dword scattered D-read that dominated stage2).
// EP_PART16: K-split partial (z-grouped XCD map), bf16 output (halves traffic).
enum { EP_BF16_BIAS = 0, EP_DMUL_LDS = 1, EP_PART16 = 2, EP_PRELU_GN = 4, EP_DUAL = 5 };

template <int MODE>
__global__ __launch_bounds__(256, 2) void gemm_bt_kernel(
    const unsigned short* __restrict__ A, int lda,
    const unsigned short* __restrict__ B, int ldb,
    void* __restrict__ Cv, int ldc, int K,
    const float* __restrict__ bias,
    const float* __restrict__ Dmul, int ldd, size_t zstride,
    const float* __restrict__ PA, const float* __restrict__ GW,
    const float* __restrict__ GB,
    const unsigned short* __restrict__ A2,
    const unsigned short* __restrict__ B2,
    const float* __restrict__ bias2) {
    __shared__ alignas(16) unsigned char SMEM[65536];
    unsigned short (*As)[8192] = (unsigned short(*)[8192])SMEM;             // [2][128*64]
    unsigned short (*Bs)[8192] = (unsigned short(*)[8192])(SMEM + 32768);   // [2][128*64]

    unsigned bx, by, zi = 0;
    if (MODE == EP_PART16) {
        // z-grouped XCD mapping: z-chunk -> XCD pair; V z-slab stays L2-hot
        unsigned gx = gridDim.x;
        unsigned L = (blockIdx.z * gridDim.y + blockIdx.y) * gx + blockIdx.x;
        unsigned xcd = L & 7u, slot = L >> 3;
        zi = xcd >> 1;
        unsigned t = slot * 2 + (xcd & 1u);
        bx = t & (gx - 1);
        by = t / gx;
    } else {
        unsigned nwg = gridDim.x * gridDim.y;
        unsigned bid = blockIdx.y * gridDim.x + blockIdx.x;
        unsigned cpx = nwg >> 3;
        bid = (bid & 7u) * cpx + (bid >> 3);
        bx = bid % gridDim.x;
        by = bid / gridDim.x;
    }
    size_t m0 = (size_t)by * 128;
    size_t nB = (size_t)bx * 128;
    size_t ncol0 = nB;

    const unsigned short* Ause = A;
    const unsigned short* Buse = B;
    const float* bias_use = bias;
    bool apply_gelu = false;
    if (MODE == EP_DUAL) {
        unsigned half = gridDim.x >> 1;
        if (bx >= half) {  // C-branch: h' @ Cw + Cb -> cols 1024..2047
            nB = (size_t)(bx - half) * 128;
            ncol0 = 1024 + nB;
            Ause = A2; Buse = B2; bias_use = bias2;
        } else {
            apply_gelu = true;
        }
    }

    int tid = threadIdx.x;
    int lane = tid & 63, w = tid >> 6;
    int wr = w >> 1, wc = w & 1;
    int cif = lane & 15;
    int rif = (lane >> 4) << 2;

    f32x4 acc[4][4];
#pragma unroll
    for (int i = 0; i < 4; ++i)
#pragma unroll
        for (int j = 0; j < 4; ++j)
#pragma unroll
            for (int r = 0; r < 4; ++r) acc[i][j][r] = 0.f;

    const unsigned short* Ablk = Ause + m0 * lda + (size_t)zi * K;
    const unsigned short* Bblk = Buse + nB * ldb + (size_t)zi * K;
    int srccol = ((lane & 7) ^ (lane >> 3)) * 8;
    int srow = w * 32 + (lane >> 3);
    int nkt = K >> 6;

    auto stage = [&](int buf, int kt) {
        int k0 = kt << 6;
        unsigned short* la = &As[buf][w * 2048];
        unsigned short* lb = &Bs[buf][w * 2048];
#pragma unroll
        for (int i = 0; i < 4; ++i) {
            __builtin_amdgcn_global_load_lds(
                (const AS1 void*)(Ablk + (size_t)(srow + i * 8) * lda + k0 + srccol),
                (AS3 void*)(la + i * 512), 16, 0, 0);
            __builtin_amdgcn_global_load_lds(
                (const AS1 void*)(Bblk + (size_t)(srow + i * 8) * ldb + k0 + srccol),
                (AS3 void*)(lb + i * 512), 16, 0, 0);
        }
    };

    stage(0, 0);
    __syncthreads();

    for (int kt = 0; kt < nkt; ++kt) {
        int cur = kt & 1;
        if (kt + 1 < nkt) stage(cur ^ 1, kt + 1);

        const bf16x8* Ap = reinterpret_cast<const bf16x8*>(As[cur]);
        const bf16x8* Bp = reinterpret_cast<const bf16x8*>(Bs[cur]);
#pragma unroll
        for (int kk = 0; kk < 2; ++kk) {
            bf16x8 af[4], bfr[4];
#pragma unroll
            for (int mi = 0; mi < 4; ++mi) {
                int row = wr * 64 + mi * 16 + (lane & 15);
                int slot = ((kk << 2) + (lane >> 4)) ^ (row & 7);
                af[mi] = Ap[row * 8 + slot];
            }
#pragma unroll
            for (int ni = 0; ni < 4; ++ni) {
                int row = wc * 64 + ni * 16 + (lane & 15);
                int slot = ((kk << 2) + (lane >> 4)) ^ (row & 7);
                bfr[ni] = Bp[row * 8 + slot];
            }
#pragma unroll
            for (int mi = 0; mi < 4; ++mi)
#pragma unroll
                for (int ni = 0; ni < 4; ++ni)
                    acc[mi][ni] = __builtin_amdgcn_mfma_f32_16x16x32_bf16(
                        af[mi], bfr[ni], acc[mi][ni], 0, 0, 0);
        }
        __syncthreads();
    }

    if (MODE == EP_DMUL_LDS) {
        // ---- coalesced D-tile staging into dead LDS (64 KB = exact fit) ----
        float4* Dl4 = (float4*)SMEM;
        int f4c = tid & 31;        // f4-col within 128-f32 row
        int r0 = tid >> 5;         // 8 row-groups
        float4 dv[16];
#pragma unroll
        for (int j = 0; j < 16; ++j)
            dv[j] = ((const float4*)(Dmul + (m0 + r0 + j * 8) * (size_t)ldd + ncol0))[f4c];
#pragma unroll
        for (int j = 0; j < 16; ++j)
            Dl4[(r0 + j * 8) * 32 + f4c] = dv[j];
        __syncthreads();
        const float* Dl = (const float*)SMEM;
        unsigned short* Cb16 = (unsigned short*)Cv;
#pragma unroll
        for (int mi = 0; mi < 4; ++mi) {
#pragma unroll
            for (int ni = 0; ni < 4; ++ni) {
                int lcol = wc * 64 + ni * 16 + cif;
                size_t gcol = ncol0 + lcol;
#pragma unroll
                for (int r = 0; r < 4; ++r) {
                    int lrow = wr * 64 + mi * 16 + rif + r;
                    float v = acc[mi][ni][r] * Dl[lrow * 128 + lcol];
                    Cb16[(m0 + lrow) * (size_t)ldc + gcol] = f2bf(v);
                }
            }
        }
        return;
    }

    if (MODE == EP_PART16) {
        unsigned short* Cp = (unsigned short*)Cv + zi * zstride;
#pragma unroll
        for (int mi = 0; mi < 4; ++mi)
#pragma unroll
            for (int ni = 0; ni < 4; ++ni) {
                size_t gcol = ncol0 + wc * 64 + ni * 16 + cif;
#pragma unroll
                for (int r = 0; r < 4; ++r) {
                    size_t grow = m0 + wr * 64 + mi * 16 + rif + r;
                    Cp[grow * (size_t)ldc + gcol] = f2bf(acc[mi][ni][r]);
                }
            }
        return;
    }

    if (MODE == EP_PRELU_GN) {
        float* Cf = (float*)Cv;
        float pbv[4], pav[4], gwv[4], gbv[4];
        size_t gcolv[4];
#pragma unroll
        for (int ni = 0; ni < 4; ++ni) {
            gcolv[ni] = ncol0 + wc * 64 + ni * 16 + cif;
            pbv[ni] = bias[gcolv[ni]];
            pav[ni] = PA[gcolv[ni]];
            gwv[ni] = GW[gcolv[ni]];
            gbv[ni] = GB[gcolv[ni]];
        }
#pragma unroll
        for (int mi = 0; mi < 4; ++mi) {
#pragma unroll
            for (int ni = 0; ni < 4; ++ni)
#pragma unroll
                for (int r = 0; r < 4; ++r) {
                    float v = acc[mi][ni][r] + pbv[ni];
                    acc[mi][ni][r] = v >= 0.f ? v : pav[ni] * v;
                }
#pragma unroll
            for (int p = 0; p < 2; ++p) {
                float s[4], ss[4];
#pragma unroll
                for (int r = 0; r < 4; ++r) {
                    float a0 = acc[mi][2 * p][r], a1 = acc[mi][2 * p + 1][r];
                    s[r] = a0 + a1;
                    ss[r] = a0 * a0 + a1 * a1;
                }
#pragma unroll
                for (int msk = 1; msk < 16; msk <<= 1)
#pragma unroll
                    for (int r = 0; r < 4; ++r) {
                        s[r] += __shfl_xor(s[r], msk);
                        ss[r] += __shfl_xor(ss[r], msk);
                    }
#pragma unroll
                for (int r = 0; r < 4; ++r) {
                    float mu = s[r] * (1.f / 32.f);
                    float inv = rsqrtf(ss[r] * (1.f / 32.f) - mu * mu + 1e-5f);
                    size_t grow = m0 + wr * 64 + mi * 16 + rif + r;
#pragma unroll
                    for (int q = 0; q < 2; ++q) {
                        int ni = 2 * p + q;
                        Cf[grow * (size_t)ldc + gcolv[ni]] =
                            (acc[mi][ni][r] - mu) * inv * gwv[ni] + gbv[ni];
                    }
                }
            }
        }
        return;
    }

#pragma unroll
    for (int mi = 0; mi < 4; ++mi) {
#pragma unroll
        for (int ni = 0; ni < 4; ++ni) {
            size_t gcol = ncol0 + wc * 64 + ni * 16 + cif;
            size_t bcol = nB + wc * 64 + ni * 16 + cif;
            float bval = bias_use ? bias_use[bcol] : 0.f;
#pragma unroll
            for (int r = 0; r < 4; ++r) {
                size_t grow = m0 + wr * 64 + mi * 16 + rif + r;
                float val = acc[mi][ni][r] + bval;
                if (MODE == EP_DUAL && apply_gelu)
                    val = 0.5f * val * (1.f + erff(val * 0.70710678118654752f));
                ((unsigned short*)Cv)[grow * (size_t)ldc + gcol] = f2bf(val);
            }
        }
    }
}

extern "C" void kernel_launch(void* const* d_in, const int* in_sizes, int n_in,
                              void* d_out, int out_size, void* d_ws, size_t ws_size,
                              hipStream_t stream) {
    constexpr int Nn = 8192, IND = 512, INTER = 512, HID = 1024, OUTD = 512;
    const float* h   = (const float*)d_in[0];
    const float* Dm  = (const float*)d_in[1];
    const float* hp  = (const float*)d_in[2];
    const float* Qw  = (const float*)d_in[3];
    const float* Qb  = (const float*)d_in[4];
    const float* Kw  = (const float*)d_in[5];
    const float* Kb  = (const float*)d_in[6];
    const float* Vw  = (const float*)d_in[7];
    const float* Vb  = (const float*)d_in[8];
    const float* Rw  = (const float*)d_in[9];
    const float* Rb  = (const float*)d_in[10];
    const float* Cw  = (const float*)d_in[11];
    const float* Cb  = (const float*)d_in[12];
    const float* Pw  = (const float*)d_in[13];
    const float* Pb  = (const float*)d_in[14];
    const float* pa  = (const float*)d_in[15];
    const float* gwt = (const float*)d_in[16];
    const float* gbt = (const float*)d_in[17];
    (void)in_sizes; (void)n_in; (void)out_size; (void)ws_size;

    char* ws = (char*)d_ws;
    size_t cur = 0;
    auto alloc = [&](size_t bytes) -> void* {
        void* p = ws + cur;
        cur += (bytes + 255) & ~(size_t)255;
        return p;
    };
    unsigned short* h_bf   = (unsigned short*)alloc((size_t)Nn * IND * 2);
    unsigned short* hp_bf  = (unsigned short*)alloc((size_t)Nn * OUTD * 2);
    unsigned short* QKVwT  = (unsigned short*)alloc((size_t)3 * INTER * IND * 2);
    float*          qkvb   = (float*)alloc((size_t)3 * INTER * 4);
    unsigned short* RwT    = (unsigned short*)alloc((size_t)INTER * HID * 2);
    unsigned short* CwT    = (unsigned short*)alloc((size_t)OUTD * HID * 2);
    unsigned short* PwT    = (unsigned short*)alloc((size_t)2 * HID * OUTD * 2);
    unsigned short* QKVm   = (unsigned short*)alloc((size_t)Nn * 3 * INTER * 2);
    unsigned short* VTm    = (unsigned short*)alloc((size_t)Nn * INTER * 2);
    unsigned short* Sm     = (unsigned short*)alloc((size_t)Nn * Nn * 2);       // 134 MB scores
    unsigned short* hret_p = (unsigned short*)alloc((size_t)4 * Nn * INTER * 2);// bf16 K-split partials
    unsigned short* hretbf = (unsigned short*)alloc((size_t)Nn * INTER * 2);
    unsigned short* comb   = Sm;  // overlay: combined (8192x2048 bf16) over dead scores

    unsigned short* Qm = QKVm;
    unsigned short* Km = QKVm + INTER;
    unsigned short* Vm = QKVm + 2 * INTER;
    const int ldqkv = 3 * INTER;

    dim3 tb(32, 8);
    int n8 = Nn * IND / 8;
    cast2_kernel<<<dim3(n8 / 256, 2), 256, 0, stream>>>(h, hp, h_bf, hp_bf, n8);

    TD6 t6;
    t6.d[0] = {Qw, QKVwT,                          INTER, IND,     16, 16};
    t6.d[1] = {Kw, QKVwT + (size_t)INTER * IND,    INTER, IND,     16, 16};
    t6.d[2] = {Vw, QKVwT + (size_t)2 * INTER * IND,INTER, IND,     16, 16};
    t6.d[3] = {Rw, RwT,                            HID,   INTER,   32, 16};
    t6.d[4] = {Cw, CwT,                            HID,   OUTD,    32, 16};
    t6.d[5] = {Pw, PwT,                            OUTD,  2 * HID, 16, 64};
    multi_transpose_kernel<<<dim3(32, 64, 6), tb, 0, stream>>>(t6);
    concat_bias_kernel<<<6, 256, 0, stream>>>(Qb, Kb, Vb, qkvb);

    // fused QKV projection: (8192 x 1536) = h @ [Qw|Kw|Vw] + [Qb|Kb|Vb]
    gemm_bt_kernel<EP_BF16_BIAS><<<dim3(3 * INTER / 128, Nn / 128), 256, 0, stream>>>(
        h_bf, IND, QKVwT, IND, QKVm, ldqkv, IND, qkvb, nullptr, 0, 0,
        nullptr, nullptr, nullptr, nullptr, nullptr, nullptr);
    transpose_bf16_kernel<<<dim3(INTER / 32, Nn / 32), tb, 0, stream>>>(Vm, ldqkv, VTm, Nn);

    // stage2: scores = D .* (Q K^T), D streamed through dead LDS in epilogue
    gemm_bt_kernel<EP_DMUL_LDS><<<dim3(Nn / 128, Nn / 128), 256, 0, stream>>>(
        Qm, ldqkv, Km, ldqkv, Sm, Nn, INTER, nullptr, Dm, Nn, 0,
        nullptr, nullptr, nullptr, nullptr, nullptr, nullptr);

    // stage3: hret = scores @ V, K-split x4 into bf16 partials (z-grouped XCDs)
    gemm_bt_kernel<EP_PART16><<<dim3(OUTD / 128, Nn / 128, 4), 256, 0, stream>>>(
        Sm, Nn, VTm, Nn, hret_p, INTER, Nn / 4, nullptr, nullptr, 0, (size_t)Nn * INTER,
        nullptr, nullptr, nullptr, nullptr, nullptr, nullptr);
    sum4b_kernel<<<(Nn * INTER / 8) / 256, 256, 0, stream>>>(
        hret_p, (size_t)Nn * INTER, hretbf, Nn * INTER / 8);

    // combined[:, :1024] = gelu(hret @ Rw + Rb) ; combined[:, 1024:] = h' @ Cw + Cb
    gemm_bt_kernel<EP_DUAL><<<dim3(2 * HID / 128, Nn / 128), 256, 0, stream>>>(
        hretbf, INTER, RwT, INTER, comb, 2 * HID, INTER, Rb, nullptr, 0, 0,
        nullptr, nullptr, nullptr, hp_bf, CwT, Cb);

    // x = combined @ Pw + Pb -> PReLU -> GroupNorm -> d_out (fp32)
    gemm_bt_kernel<EP_PRELU_GN><<<dim3(OUTD / 128, Nn / 128), 256, 0, stream>>>(
        comb, 2 * HID, PwT, 2 * HID, d_out, OUTD, 2 * HID, Pb, nullptr, 0, 0,
        pa, gwt, gbt, nullptr, nullptr, nullptr);
}